// Round 2
// baseline (504.890 us; speedup 1.0000x reference)
//
#include <hip/hip_runtime.h>

typedef unsigned long long ull;

#define MMAX 64  // M, M2 = 32 in practice; headroom to 64

// ---------------------------------------------------------------------------
// K1 k_iou: per-(b,anchor) row max/argmax over M gt boxes (pre-force bto/bti),
// per-block column-argmax partials (packed (iou_bits<<32)|~a keys) and
// per-block count of pre-force positives. No atomics -> no init kernel.
// 4x thread coarsening amortizes the per-j wave reduction.
// ---------------------------------------------------------------------------
__global__ void k_iou(const float* __restrict__ anchors, const float* __restrict__ ann1,
                      float* __restrict__ bto, int* __restrict__ bti,
                      ull* __restrict__ part_key, int* __restrict__ part_cnt,
                      int A, int M, int NBLK) {
    __shared__ float s_box[MMAX][4];
    __shared__ float s_area[MMAX];
    __shared__ ull s_part[4][MMAX];
    __shared__ int s_cnt[4];
    const int b = blockIdx.y;
    const int blk = blockIdx.x;
    const int tid = threadIdx.x;
    for (int i = tid; i < M; i += blockDim.x) {
        const float* g = ann1 + ((size_t)b * M + i) * 6;
        float x1 = g[0], y1 = g[1], x2 = g[2], y2 = g[3];
        s_box[i][0] = x1; s_box[i][1] = y1; s_box[i][2] = x2; s_box[i][3] = y2;
        s_area[i] = (x2 - x1) * (y2 - y1);
    }
    __syncthreads();

    const int base = blk * (blockDim.x * 4);
    float ax1[4], ay1[4], ax2[4], ay2[4], aar[4];
    int aidx[4]; bool val[4];
#pragma unroll
    for (int u = 0; u < 4; ++u) {
        int a = base + u * blockDim.x + tid;
        aidx[u] = a; val[u] = (a < A);
        float4 av = make_float4(0.f, 0.f, 0.f, 0.f);
        if (val[u]) av = ((const float4*)anchors)[a];
        ax1[u] = av.x; ay1[u] = av.y; ax2[u] = av.z; ay2[u] = av.w;
        aar[u] = (av.z - av.x) * (av.w - av.y);
    }
    float best[4] = {-1.f, -1.f, -1.f, -1.f};
    int bestj[4] = {0, 0, 0, 0};
    const int lane = tid & 63, wid = tid >> 6;

    for (int j = 0; j < M; ++j) {
        float bx1 = s_box[j][0], by1 = s_box[j][1], bx2 = s_box[j][2], by2 = s_box[j][3];
        float bar = s_area[j];
        ull key = 0ull;
#pragma unroll
        for (int u = 0; u < 4; ++u) {
            float iw = fmaxf(fminf(ax2[u], bx2) - fmaxf(ax1[u], bx1), 0.f);
            float ih = fmaxf(fminf(ay2[u], by2) - fmaxf(ay1[u], by1), 0.f);
            float inter = iw * ih;
            float ua = fmaxf(aar[u] + bar - inter, 1e-8f);
            float iou = inter / ua;
            if (val[u]) {
                if (iou > best[u]) { best[u] = iou; bestj[u] = j; }  // strict > => first occurrence (jnp.argmax axis=1)
                ull k2 = (((ull)__float_as_uint(iou)) << 32) | (ull)(0xFFFFFFFFu - (unsigned)aidx[u]);
                if (k2 > key) key = k2;  // ~a in low word => ties pick min anchor idx (jnp.argmax axis=0)
            }
        }
#pragma unroll
        for (int off = 32; off > 0; off >>= 1) {
            ull o = __shfl_down(key, off);
            if (o > key) key = o;
        }
        if (lane == 0) s_part[wid][j] = key;
    }
    int cnt = 0;
#pragma unroll
    for (int u = 0; u < 4; ++u) {
        if (val[u]) {
            bto[(size_t)b * A + aidx[u]] = best[u];
            bti[(size_t)b * A + aidx[u]] = bestj[u];
            if (best[u] >= 0.5f) ++cnt;
        }
    }
#pragma unroll
    for (int off = 32; off > 0; off >>= 1) cnt += __shfl_down(cnt, off);
    if (lane == 0) s_cnt[wid] = cnt;
    __syncthreads();
    if (tid < M) {
        ull key = s_part[0][tid];
        if (s_part[1][tid] > key) key = s_part[1][tid];
        if (s_part[2][tid] > key) key = s_part[2][tid];
        if (s_part[3][tid] > key) key = s_part[3][tid];
        part_key[((size_t)b * NBLK + blk) * M + tid] = key;
    }
    if (tid == 0) part_cnt[b * NBLK + blk] = s_cnt[0] + s_cnt[1] + s_cnt[2] + s_cnt[3];
}

// ---------------------------------------------------------------------------
// K2 k_assign: one wave per sample. Reduces column partials -> bpi, applies
// force-assign (bto=2.0; bti[a]=max j owning a, == torch last-write-wins),
// computes npos[b] = pre-force positives + newly-forced anchors, zeroes out.
// ---------------------------------------------------------------------------
__global__ void k_assign(const ull* __restrict__ part_key, const int* __restrict__ part_cnt,
                         float* __restrict__ bto, int* __restrict__ bti,
                         int* __restrict__ npos, float* __restrict__ out,
                         int A, int M, int NBLK) {
    const int b = blockIdx.x;
    const int tid = threadIdx.x;  // 64 threads = 1 wave
    __shared__ int s_a[MMAX];
    if (tid < M) {
        ull key = 0ull;
        for (int k = 0; k < NBLK; ++k) {
            ull v = part_key[((size_t)b * NBLK + k) * M + tid];
            if (v > key) key = v;
        }
        s_a[tid] = (int)(0xFFFFFFFFu - (unsigned)(key & 0xFFFFFFFFull));
    }
    __syncthreads();
    int corr = 0;
    if (tid < M) {
        int a = s_a[tid];
        bool owner = true;  // owner = largest j mapped to this anchor
        for (int j2 = tid + 1; j2 < M; ++j2)
            if (s_a[j2] == a) owner = false;
        if (owner) {
            float pre = bto[(size_t)b * A + a];
            bto[(size_t)b * A + a] = 2.0f;
            bti[(size_t)b * A + a] = tid;
            if (pre < 0.5f) corr = 1;  // anchor newly became positive
        }
    }
    int cnt = corr;
    for (int k = tid; k < NBLK; k += 64) cnt += part_cnt[b * NBLK + k];
#pragma unroll
    for (int off = 32; off > 0; off >>= 1) cnt += __shfl_down(cnt, off);
    if (tid == 0) npos[b] = cnt;
    if (b == 0 && tid == 0) { out[0] = 0.f; out[1] = 0.f; }
}

// ---------------------------------------------------------------------------
// K3 k_main: fused focal cls loss + smooth-L1 reg loss. Grid-stride over
// float4 of [A,C] per sample; the thread owning column-block 0 of an anchor
// also does the reg work for that anchor. Block partials are normalized by
// npos[b] and atomically accumulated straight into out[0..1].
// ---------------------------------------------------------------------------
template <int C4C>
__global__ __launch_bounds__(256, 4)
void k_main(const float* __restrict__ cls, const float* __restrict__ regs,
            const float* __restrict__ anchors,
            const float* __restrict__ ann1, const float* __restrict__ ann2,
            const float* __restrict__ bto, const int* __restrict__ bti,
            const int* __restrict__ npos, float* __restrict__ out,
            int A, int c4_rt, int M, int M2, float invB) {
    const int c4 = (C4C > 0) ? C4C : c4_rt;
    const int b = blockIdx.y;
    const int tid = threadIdx.x;
    __shared__ float s_a1[MMAX * 6];
    __shared__ float s_a2[MMAX * 6];
    for (int i = tid; i < M * 6; i += blockDim.x) s_a1[i] = ann1[(size_t)b * M * 6 + i];
    for (int i = tid; i < M2 * 6; i += blockDim.x) s_a2[i] = ann2[(size_t)b * M2 * 6 + i];
    __syncthreads();

    const int N4 = A * c4;
    const float4* cb = (const float4*)(cls + (size_t)b * A * (c4 * 4));
    const float* btob = bto + (size_t)b * A;
    const int* btib = bti + (size_t)b * A;
    float lsum = 0.f, rsum = 0.f;
    const int stride = gridDim.x * blockDim.x;
    for (int i = blockIdx.x * blockDim.x + tid; i < N4; i += stride) {
        int a = i / c4;
        int c0 = (i - a * c4) * 4;
        float v = btob[a];
        bool pos = (v >= 0.5f), neg = (v < 0.4f);
        if (pos || neg) {  // ignore band contributes 0 and skips the load
            float4 x = cb[i];
            int label = pos ? (int)s_a1[btib[a] * 6 + 4] : -1;
            float xs[4] = {x.x, x.y, x.z, x.w};
#pragma unroll
            for (int k = 0; k < 4; ++k) {
                float p = fminf(fmaxf(xs[k], 1e-4f), 1.0f - 1e-4f);
                if (pos && (c0 + k) == label) {
                    float q = 1.f - p;
                    lsum += 0.25f * q * q * (-__logf(p));
                } else {
                    lsum += 0.75f * p * p * (-__logf(1.f - p));
                }
            }
        }
        if (pos && c0 == 0) {  // this thread owns anchor a's reg work
            const int ji = btib[a];
            const float* as = &s_a1[ji * 6];
            float4 av = ((const float4*)anchors)[a];
            float aw = av.z - av.x, ah = av.w - av.y;
            float acx = av.x + 0.5f * aw, acy = av.y + 0.5f * ah;
            float gw0 = as[2] - as[0], gh0 = as[3] - as[1];
            float gcx = as[0] + 0.5f * gw0, gcy = as[1] + 0.5f * gh0;
            float gw = fmaxf(gw0, 1.f), gh = fmaxf(gh0, 1.f);
            float t[8];
            t[0] = ((gcx - acx) / aw) / 0.1f;
            t[1] = ((gcy - acy) / ah) / 0.1f;
            t[2] = __logf(gw / aw) / 0.2f;
            t[3] = __logf(gh / ah) / 0.2f;
            int nterm = 4;
            float tid5 = as[5];
            int first = -1;
            for (int j2 = 0; j2 < M2; ++j2) {
                if (s_a2[j2 * 6 + 5] == tid5) { first = j2; break; }  // first match
            }
            if (first >= 0) {
                const float* ns = &s_a2[first * 6];
                float nw0 = ns[2] - ns[0], nh0 = ns[3] - ns[1];
                float ncx = ns[0] + 0.5f * nw0, ncy = ns[1] + 0.5f * nh0;
                float nw = fmaxf(nw0, 1.f), nh = fmaxf(nh0, 1.f);
                t[4] = ((ncx - acx) / aw) / 0.1f;
                t[5] = ((ncy - acy) / ah) / 0.1f;
                t[6] = __logf(nw / aw) / 0.2f;
                t[7] = __logf(nh / ah) / 0.2f;
                nterm = 8;
            }
            const float* rg = regs + ((size_t)b * A + a) * 8;
            for (int k = 0; k < nterm; ++k) {
                float d = fabsf(t[k] - rg[k]);
                rsum += (d <= (1.0f / 9.0f)) ? (4.5f * d * d) : (d - (0.5f / 9.0f));
            }
        }
    }
#pragma unroll
    for (int off = 32; off > 0; off >>= 1) {
        lsum += __shfl_down(lsum, off);
        rsum += __shfl_down(rsum, off);
    }
    __shared__ float s_l[4], s_r[4];
    if ((tid & 63) == 0) { s_l[tid >> 6] = lsum; s_r[tid >> 6] = rsum; }
    __syncthreads();
    if (tid == 0) {
        float np_ = (float)npos[b];
        float l = (s_l[0] + s_l[1] + s_l[2] + s_l[3]) / fmaxf(np_, 1.f) * invB;
        float r = (s_r[0] + s_r[1] + s_r[2] + s_r[3]) / fmaxf(np_ * 8.f, 1.f) * invB;
        atomicAdd(&out[0], l);
        atomicAdd(&out[1], r);
    }
}

extern "C" void kernel_launch(void* const* d_in, const int* in_sizes, int n_in,
                              void* d_out, int out_size, void* d_ws, size_t ws_size,
                              hipStream_t stream) {
    const float* cls = (const float*)d_in[0];
    const float* regs = (const float*)d_in[1];
    const float* anchors = (const float*)d_in[2];
    const float* ann1 = (const float*)d_in[3];
    const float* ann2 = (const float*)d_in[4];
    float* out = (float*)d_out;

    const int A = in_sizes[2] / 4;           // anchors [1,A,4]
    const int B = in_sizes[1] / (A * 8);     // regressions [B,A,8]
    const int C = in_sizes[0] / (B * A);     // classifications [B,A,C]
    const int M = in_sizes[3] / (B * 6);     // annotations1 [B,M,6]
    const int M2 = in_sizes[4] / (B * 6);    // annotations2 [B,M2,6]
    const int NBLK = (A + 1023) / 1024;

    char* ws = (char*)d_ws;
    size_t off = 0;
    float* bto = (float*)(ws + off);     off += (size_t)B * A * sizeof(float);        off = (off + 255) & ~(size_t)255;
    int* bti = (int*)(ws + off);         off += (size_t)B * A * sizeof(int);          off = (off + 255) & ~(size_t)255;
    ull* part_key = (ull*)(ws + off);    off += (size_t)B * NBLK * M * sizeof(ull);   off = (off + 255) & ~(size_t)255;
    int* part_cnt = (int*)(ws + off);    off += (size_t)B * NBLK * sizeof(int);       off = (off + 255) & ~(size_t)255;
    int* npos = (int*)(ws + off);        off += (size_t)B * sizeof(int);

    dim3 g1(NBLK, B);
    k_iou<<<g1, dim3(256), 0, stream>>>(anchors, ann1, bto, bti, part_key, part_cnt, A, M, NBLK);

    k_assign<<<dim3(B), dim3(64), 0, stream>>>(part_key, part_cnt, bto, bti, npos, out, A, M, NBLK);

    dim3 g3(512, B);
    const float invB = 1.0f / (float)B;
    if (C == 80)
        k_main<20><<<g3, dim3(256), 0, stream>>>(cls, regs, anchors, ann1, ann2, bto, bti,
                                                 npos, out, A, C / 4, M, M2, invB);
    else
        k_main<0><<<g3, dim3(256), 0, stream>>>(cls, regs, anchors, ann1, ann2, bto, bti,
                                                npos, out, A, C / 4, M, M2, invB);
}

// Round 3
// 480.880 us; speedup vs baseline: 1.0499x; 1.0499x over previous
//
#include <hip/hip_runtime.h>

typedef unsigned long long ull;

#define MMAX 64  // M, M2 = 32 in practice; headroom to 64

// ---------------------------------------------------------------------------
// K1 k_iou: per-(b,anchor) row max/argmax over M gt boxes -> bto/bti/acode,
// per-block column-argmax partials (packed (iou_bits<<32)|~a keys) and
// per-block count of pre-force positives. No atomics -> no init kernel.
// acode: >=0 positive (label), -1 negative, -2 ignore band.
// ---------------------------------------------------------------------------
__global__ void k_iou(const float* __restrict__ anchors, const float* __restrict__ ann1,
                      float* __restrict__ bto, int* __restrict__ bti, int* __restrict__ acode,
                      ull* __restrict__ part_key, int* __restrict__ part_cnt,
                      int A, int M, int NBLK) {
    __shared__ float s_box[MMAX][4];
    __shared__ float s_area[MMAX];
    __shared__ float s_lab[MMAX];
    __shared__ ull s_part[4][MMAX];
    __shared__ int s_cnt[4];
    const int b = blockIdx.y;
    const int blk = blockIdx.x;
    const int tid = threadIdx.x;
    for (int i = tid; i < M; i += blockDim.x) {
        const float* g = ann1 + ((size_t)b * M + i) * 6;
        float x1 = g[0], y1 = g[1], x2 = g[2], y2 = g[3];
        s_box[i][0] = x1; s_box[i][1] = y1; s_box[i][2] = x2; s_box[i][3] = y2;
        s_area[i] = (x2 - x1) * (y2 - y1);
        s_lab[i] = g[4];
    }
    __syncthreads();

    const int base = blk * (blockDim.x * 4);
    float ax1[4], ay1[4], ax2[4], ay2[4], aar[4];
    int aidx[4]; bool val[4];
#pragma unroll
    for (int u = 0; u < 4; ++u) {
        int a = base + u * blockDim.x + tid;
        aidx[u] = a; val[u] = (a < A);
        float4 av = make_float4(0.f, 0.f, 0.f, 0.f);
        if (val[u]) av = ((const float4*)anchors)[a];
        ax1[u] = av.x; ay1[u] = av.y; ax2[u] = av.z; ay2[u] = av.w;
        aar[u] = (av.z - av.x) * (av.w - av.y);
    }
    float best[4] = {-1.f, -1.f, -1.f, -1.f};
    int bestj[4] = {0, 0, 0, 0};
    const int lane = tid & 63, wid = tid >> 6;

    for (int j = 0; j < M; ++j) {
        float bx1 = s_box[j][0], by1 = s_box[j][1], bx2 = s_box[j][2], by2 = s_box[j][3];
        float bar = s_area[j];
        ull key = 0ull;
#pragma unroll
        for (int u = 0; u < 4; ++u) {
            float iw = fmaxf(fminf(ax2[u], bx2) - fmaxf(ax1[u], bx1), 0.f);
            float ih = fmaxf(fminf(ay2[u], by2) - fmaxf(ay1[u], by1), 0.f);
            float inter = iw * ih;
            float ua = fmaxf(aar[u] + bar - inter, 1e-8f);
            float iou = inter / ua;
            if (val[u]) {
                if (iou > best[u]) { best[u] = iou; bestj[u] = j; }  // strict > => first occurrence (argmax axis=1)
                ull k2 = (((ull)__float_as_uint(iou)) << 32) | (ull)(0xFFFFFFFFu - (unsigned)aidx[u]);
                if (k2 > key) key = k2;  // ~a low word => ties pick min anchor idx (argmax axis=0)
            }
        }
#pragma unroll
        for (int off = 32; off > 0; off >>= 1) {
            ull o = __shfl_down(key, off);
            if (o > key) key = o;
        }
        if (lane == 0) s_part[wid][j] = key;
    }
    int cnt = 0;
#pragma unroll
    for (int u = 0; u < 4; ++u) {
        if (val[u]) {
            float bv = best[u];
            bto[(size_t)b * A + aidx[u]] = bv;
            bti[(size_t)b * A + aidx[u]] = bestj[u];
            int code;
            if (bv >= 0.5f) { code = (int)s_lab[bestj[u]]; ++cnt; }
            else code = (bv < 0.4f) ? -1 : -2;
            acode[(size_t)b * A + aidx[u]] = code;
        }
    }
#pragma unroll
    for (int off = 32; off > 0; off >>= 1) cnt += __shfl_down(cnt, off);
    if (lane == 0) s_cnt[wid] = cnt;
    __syncthreads();
    if (tid < M) {
        ull key = s_part[0][tid];
        if (s_part[1][tid] > key) key = s_part[1][tid];
        if (s_part[2][tid] > key) key = s_part[2][tid];
        if (s_part[3][tid] > key) key = s_part[3][tid];
        part_key[((size_t)b * NBLK + blk) * M + tid] = key;
    }
    if (tid == 0) part_cnt[b * NBLK + blk] = s_cnt[0] + s_cnt[1] + s_cnt[2] + s_cnt[3];
}

// ---------------------------------------------------------------------------
// K2 k_assign: one wave per sample. Reduces column partials, applies
// force-assign (bto=2.0; bti/acode from owner j = max j, torch last-write-wins),
// computes npos[b], zeroes out[0..1].
// ---------------------------------------------------------------------------
__global__ void k_assign(const ull* __restrict__ part_key, const int* __restrict__ part_cnt,
                         const float* __restrict__ ann1,
                         float* __restrict__ bto, int* __restrict__ bti, int* __restrict__ acode,
                         int* __restrict__ npos, float* __restrict__ out,
                         int A, int M, int NBLK) {
    const int b = blockIdx.x;
    const int tid = threadIdx.x;  // 64 threads = 1 wave
    __shared__ int s_a[MMAX];
    if (tid < M) {
        ull key = 0ull;
        for (int k = 0; k < NBLK; ++k) {
            ull v = part_key[((size_t)b * NBLK + k) * M + tid];
            if (v > key) key = v;
        }
        s_a[tid] = (int)(0xFFFFFFFFu - (unsigned)(key & 0xFFFFFFFFull));
    }
    __syncthreads();
    int corr = 0;
    if (tid < M) {
        int a = s_a[tid];
        bool owner = true;  // owner = largest j mapped to this anchor
        for (int j2 = tid + 1; j2 < M; ++j2)
            if (s_a[j2] == a) owner = false;
        if (owner) {
            float pre = bto[(size_t)b * A + a];
            bto[(size_t)b * A + a] = 2.0f;
            bti[(size_t)b * A + a] = tid;
            acode[(size_t)b * A + a] = (int)ann1[((size_t)b * M + tid) * 6 + 4];
            if (pre < 0.5f) corr = 1;  // anchor newly became positive
        }
    }
    int cnt = corr;
    for (int k = tid; k < NBLK; k += 64) cnt += part_cnt[b * NBLK + k];
#pragma unroll
    for (int off = 32; off > 0; off >>= 1) cnt += __shfl_down(cnt, off);
    if (tid == 0) npos[b] = cnt;
    if (b == 0 && tid == 0) { out[0] = 0.f; out[1] = 0.f; }
}

// ---------------------------------------------------------------------------
// K3 k_cls: pure streaming focal loss. Branch-free background term for all
// elements (w=0 for ignore band), rare correction branch swaps in the
// foreground term for the label element of positive anchors.
// 4 float4 loads in flight per thread per super-iteration.
// ---------------------------------------------------------------------------
__device__ __forceinline__ float bg_term(float x) {
    float p = fminf(fmaxf(x, 1e-4f), 1.0f - 1e-4f);
    return p * p * (-__logf(1.0f - p));   // x 0.75 folded in later
}

template <int C4C>
__global__ __launch_bounds__(256, 4)
void k_cls(const float* __restrict__ cls, const int* __restrict__ acode,
           const int* __restrict__ npos, float* __restrict__ out,
           int A, int c4_rt, float invB) {
    const int c4 = (C4C > 0) ? C4C : c4_rt;
    const int b = blockIdx.y;
    const int tid = threadIdx.x;
    const int N4 = A * c4;
    const float4* cb = (const float4*)(cls + (size_t)b * A * (c4 * 4));
    const int* ac = acode + (size_t)b * A;
    float lsum = 0.f;
    const int stride = gridDim.x * blockDim.x;
    int i = blockIdx.x * blockDim.x + tid;

    for (; i + 3 * stride < N4; i += 4 * stride) {
        int idx[4], code[4];
        float4 x[4];
#pragma unroll
        for (int u = 0; u < 4; ++u) { idx[u] = i + u * stride; code[u] = ac[idx[u] / c4]; }
#pragma unroll
        for (int u = 0; u < 4; ++u) x[u] = cb[idx[u]];
#pragma unroll
        for (int u = 0; u < 4; ++u) {
            float tmp = bg_term(x[u].x) + bg_term(x[u].y) + bg_term(x[u].z) + bg_term(x[u].w);
            float w = (code[u] == -2) ? 0.f : 0.75f;
            lsum = fmaf(w, tmp, lsum);
            int c0 = (idx[u] - (idx[u] / c4) * c4) * 4;
            int rel = code[u] - c0;
            if (((unsigned)rel) < 4u) {  // label element lives in this float4 (pos anchors only)
                float xs = (rel == 0) ? x[u].x : (rel == 1) ? x[u].y : (rel == 2) ? x[u].z : x[u].w;
                float p = fminf(fmaxf(xs, 1e-4f), 1.0f - 1e-4f);
                float q = 1.f - p;
                lsum -= 0.75f * p * p * (-__logf(q));     // remove bg term
                lsum += 0.25f * q * q * (-__logf(p));     // add fg term
            }
        }
    }
    for (; i < N4; i += stride) {
        int code = ac[i / c4];
        float4 x = cb[i];
        float tmp = bg_term(x.x) + bg_term(x.y) + bg_term(x.z) + bg_term(x.w);
        float w = (code == -2) ? 0.f : 0.75f;
        lsum = fmaf(w, tmp, lsum);
        int c0 = (i - (i / c4) * c4) * 4;
        int rel = code - c0;
        if (((unsigned)rel) < 4u) {
            float xs = (rel == 0) ? x.x : (rel == 1) ? x.y : (rel == 2) ? x.z : x.w;
            float p = fminf(fmaxf(xs, 1e-4f), 1.0f - 1e-4f);
            float q = 1.f - p;
            lsum -= 0.75f * p * p * (-__logf(q));
            lsum += 0.25f * q * q * (-__logf(p));
        }
    }
#pragma unroll
    for (int off = 32; off > 0; off >>= 1) lsum += __shfl_down(lsum, off);
    __shared__ float s_l[4];
    if ((tid & 63) == 0) s_l[tid >> 6] = lsum;
    __syncthreads();
    if (tid == 0) {
        float np_ = (float)npos[b];
        atomicAdd(&out[0], (s_l[0] + s_l[1] + s_l[2] + s_l[3]) / fmaxf(np_, 1.f) * invB);
    }
}

// ---------------------------------------------------------------------------
// K4 k_reg: smooth-L1 regression loss over positive anchors, normalized and
// accumulated straight into out[1].
// ---------------------------------------------------------------------------
__global__ void k_reg(const float* __restrict__ anchors, const float* __restrict__ ann1,
                      const float* __restrict__ ann2, const float* __restrict__ regs,
                      const float* __restrict__ bto, const int* __restrict__ bti,
                      const int* __restrict__ npos, float* __restrict__ out,
                      int A, int M, int M2, float invB) {
    __shared__ float s_a1[MMAX * 6];
    __shared__ float s_a2[MMAX * 6];
    const int b = blockIdx.y;
    const int tid = threadIdx.x;
    for (int i = tid; i < M * 6; i += blockDim.x) s_a1[i] = ann1[(size_t)b * M * 6 + i];
    for (int i = tid; i < M2 * 6; i += blockDim.x) s_a2[i] = ann2[(size_t)b * M2 * 6 + i];
    __syncthreads();

    const int a = blockIdx.x * blockDim.x + tid;
    float sum = 0.f;
    if (a < A) {
        float v = bto[(size_t)b * A + a];
        if (v >= 0.5f) {
            const int ji = bti[(size_t)b * A + a];
            const float* as = &s_a1[ji * 6];
            float4 av = ((const float4*)anchors)[a];
            float aw = av.z - av.x, ah = av.w - av.y;
            float acx = av.x + 0.5f * aw, acy = av.y + 0.5f * ah;
            float gw0 = as[2] - as[0], gh0 = as[3] - as[1];
            float gcx = as[0] + 0.5f * gw0, gcy = as[1] + 0.5f * gh0;
            float gw = fmaxf(gw0, 1.f), gh = fmaxf(gh0, 1.f);
            float t[8];
            t[0] = ((gcx - acx) / aw) / 0.1f;
            t[1] = ((gcy - acy) / ah) / 0.1f;
            t[2] = __logf(gw / aw) / 0.2f;
            t[3] = __logf(gh / ah) / 0.2f;
            int nterm = 4;
            float tid5 = as[5];
            int first = -1;
            for (int j2 = 0; j2 < M2; ++j2) {
                if (s_a2[j2 * 6 + 5] == tid5) { first = j2; break; }  // first match
            }
            if (first >= 0) {
                const float* ns = &s_a2[first * 6];
                float nw0 = ns[2] - ns[0], nh0 = ns[3] - ns[1];
                float ncx = ns[0] + 0.5f * nw0, ncy = ns[1] + 0.5f * nh0;
                float nw = fmaxf(nw0, 1.f), nh = fmaxf(nh0, 1.f);
                t[4] = ((ncx - acx) / aw) / 0.1f;
                t[5] = ((ncy - acy) / ah) / 0.1f;
                t[6] = __logf(nw / aw) / 0.2f;
                t[7] = __logf(nh / ah) / 0.2f;
                nterm = 8;
            }
            const float* rg = regs + ((size_t)b * A + a) * 8;
            for (int k = 0; k < nterm; ++k) {
                float d = fabsf(t[k] - rg[k]);
                sum += (d <= (1.0f / 9.0f)) ? (4.5f * d * d) : (d - (0.5f / 9.0f));
            }
        }
    }
#pragma unroll
    for (int off = 32; off > 0; off >>= 1) sum += __shfl_down(sum, off);
    __shared__ float s_rs[4];
    if ((tid & 63) == 0) s_rs[tid >> 6] = sum;
    __syncthreads();
    if (tid == 0) {
        float s = s_rs[0] + s_rs[1] + s_rs[2] + s_rs[3];
        if (s != 0.f) {
            float np_ = (float)npos[b];
            atomicAdd(&out[1], s / fmaxf(np_ * 8.f, 1.f) * invB);
        }
    }
}

extern "C" void kernel_launch(void* const* d_in, const int* in_sizes, int n_in,
                              void* d_out, int out_size, void* d_ws, size_t ws_size,
                              hipStream_t stream) {
    const float* cls = (const float*)d_in[0];
    const float* regs = (const float*)d_in[1];
    const float* anchors = (const float*)d_in[2];
    const float* ann1 = (const float*)d_in[3];
    const float* ann2 = (const float*)d_in[4];
    float* out = (float*)d_out;

    const int A = in_sizes[2] / 4;           // anchors [1,A,4]
    const int B = in_sizes[1] / (A * 8);     // regressions [B,A,8]
    const int C = in_sizes[0] / (B * A);     // classifications [B,A,C]
    const int M = in_sizes[3] / (B * 6);     // annotations1 [B,M,6]
    const int M2 = in_sizes[4] / (B * 6);    // annotations2 [B,M2,6]
    const int NBLK = (A + 1023) / 1024;

    char* ws = (char*)d_ws;
    size_t off = 0;
    float* bto = (float*)(ws + off);     off += (size_t)B * A * sizeof(float);        off = (off + 255) & ~(size_t)255;
    int* bti = (int*)(ws + off);         off += (size_t)B * A * sizeof(int);          off = (off + 255) & ~(size_t)255;
    int* acode = (int*)(ws + off);       off += (size_t)B * A * sizeof(int);          off = (off + 255) & ~(size_t)255;
    ull* part_key = (ull*)(ws + off);    off += (size_t)B * NBLK * M * sizeof(ull);   off = (off + 255) & ~(size_t)255;
    int* part_cnt = (int*)(ws + off);    off += (size_t)B * NBLK * sizeof(int);       off = (off + 255) & ~(size_t)255;
    int* npos = (int*)(ws + off);        off += (size_t)B * sizeof(int);

    dim3 g1(NBLK, B);
    k_iou<<<g1, dim3(256), 0, stream>>>(anchors, ann1, bto, bti, acode, part_key, part_cnt, A, M, NBLK);

    k_assign<<<dim3(B), dim3(64), 0, stream>>>(part_key, part_cnt, ann1, bto, bti, acode, npos, out, A, M, NBLK);

    dim3 g3(512, B);
    const float invB = 1.0f / (float)B;
    if (C == 80)
        k_cls<20><<<g3, dim3(256), 0, stream>>>(cls, acode, npos, out, A, C / 4, invB);
    else
        k_cls<0><<<g3, dim3(256), 0, stream>>>(cls, acode, npos, out, A, C / 4, invB);

    dim3 g4((A + 255) / 256, B);
    k_reg<<<g4, dim3(256), 0, stream>>>(anchors, ann1, ann2, regs, bto, bti, npos, out, A, M, M2, invB);
}